// Round 6
// baseline (11988.808 us; speedup 1.0000x reference)
//
#include <hip/hip_runtime.h>
#include <cstdint>
#include <cstddef>

// ---------------------------------------------------------------------------
// 3-layer LSTMP, folded projection, ONE persistent kernel, fence-free loop.
//   u_t = o*tanh(c);  gates_t = in_t@Wx + u_{t-1}@(Wp@Wh) + b
//   seq h_t = u_t@Wp (16 of 48 WGs, post-arrive, 1-step lag); c in registers;
//   layer-carry h via in-register trans GEMM accInit = h_final @ Wh_next.
// Geometry: 4 batch-groups (one per XCD pair) x 48 WGs; WG = 64 rows x 64
// gate-cols; wave = 16 rows, 4 gate-tiles (gates lane-local). B (128KB) in
// swizzled LDS, staged once per layer.
// Cross-WG protocol (r6): U written sc0/sc1 (write-through to MALL) + drained
// before per-WG epoch-flag store (sc0/sc1). Readers spin on flags (uncached),
// then ONE acquire-fence (vL1+L2 inv) per WG, then CACHED U loads -> 24
// WGs/XCD share the U fill through L2 instead of 24x MALL re-reads.
// ---------------------------------------------------------------------------

typedef __attribute__((ext_vector_type(8))) short bf16x8;
typedef __attribute__((ext_vector_type(4))) float f32x4;
typedef __attribute__((ext_vector_type(2))) int i32x2;

#define TT 400
#define NB 256
#define IIP 96
#define HH 768
#define PP 256
#define G4 3072
#define WGJ 48
#define SMEMB (131072 + 2048)

__device__ __forceinline__ short f2bf(float f) {
  unsigned u = __builtin_bit_cast(unsigned, f);
  unsigned r = u + 0x7FFFu + ((u >> 16) & 1u);
  return (short)(r >> 16);
}
__device__ __forceinline__ float sigf(float x) { return 1.0f / (1.0f + __expf(-x)); }
__device__ __forceinline__ float tanh_(float x) { return 1.0f - 2.0f / (__expf(2.0f * x) + 1.0f); }

// ---- coherent (sc0 sc1) memory ops ----
__device__ __forceinline__ void ld_co(bf16x8* d, const void* p) {
  asm volatile("global_load_dwordx4 %0, %1, off sc0 sc1" : "=v"(*d) : "v"(p));
}
__device__ __forceinline__ void st_co_b64(void* p, i32x2 v) {
  asm volatile("global_store_dwordx2 %0, %1, off sc0 sc1" :: "v"(p), "v"(v) : "memory");
}
__device__ __forceinline__ void st_co_b32(void* p, int v) {
  asm volatile("global_store_dword %0, %1, off sc0 sc1" :: "v"(p), "v"(v) : "memory");
}
__device__ __forceinline__ void st_co_b16(void* p, int v) {
  asm volatile("global_store_short %0, %1, off sc0 sc1" :: "v"(p), "v"(v) : "memory");
}
#define WAIT_TIE24(u) \
  asm volatile("s_waitcnt vmcnt(0)" \
    : "+v"(u[0]),"+v"(u[1]),"+v"(u[2]),"+v"(u[3]),"+v"(u[4]),"+v"(u[5]), \
      "+v"(u[6]),"+v"(u[7]),"+v"(u[8]),"+v"(u[9]),"+v"(u[10]),"+v"(u[11]), \
      "+v"(u[12]),"+v"(u[13]),"+v"(u[14]),"+v"(u[15]),"+v"(u[16]),"+v"(u[17]), \
      "+v"(u[18]),"+v"(u[19]),"+v"(u[20]),"+v"(u[21]),"+v"(u[22]),"+v"(u[23]))

// --------------------------- prep kernels ----------------------------------
// n' mapping: j = n'>>6, wj = n'&63, gate = wj>>4, cc = wj&15
//             col = gate*768 + j*16 + cc

__global__ void k_xb(const float* __restrict__ x, short* __restrict__ xb) {
  int idx = blockIdx.x * 256 + threadIdx.x;
  if (idx >= TT * NB * 80) return;
  int i = idx % 80, tb = idx / 80;
  int b = tb % NB, t = tb / NB;
  xb[(size_t)(t * NB + b) * IIP + i] = f2bf(x[(size_t)(b * TT + t) * 80 + i]);
}

__global__ void k_makeB(const float* __restrict__ Wx, const float* __restrict__ Wp,
                        const float* __restrict__ Wh, short* __restrict__ out,
                        int K, int KIN, int INDIM) {
  int np = blockIdx.x * 256 + threadIdx.x;
  int k = blockIdx.y;
  int j2 = np >> 6, wj = np & 63, ntg = wj >> 4, cc = wj & 15;
  int col = ntg * HH + j2 * 16 + cc;
  float v;
  if (k < KIN) {
    v = (k < INDIM) ? Wx[(size_t)k * G4 + col] : 0.0f;
  } else {
    float a = 0.f;
    int kr = k - KIN;
    for (int q = 0; q < PP; ++q)
      a = fmaf(Wp[(size_t)kr * PP + q], Wh[(size_t)q * G4 + col], a);
    v = a;
  }
  out[(size_t)np * K + k] = f2bf(v);
}

__global__ void k_wpT(const float* __restrict__ Wp, short* __restrict__ WpT) {
  int idx = blockIdx.x * 256 + threadIdx.x;
  if (idx >= PP * HH) return;
  int n = idx % PP, k = idx / PP;
  WpT[(size_t)n * HH + k] = f2bf(Wp[(size_t)k * PP + n]);
}

__global__ void k_whT(const float* __restrict__ Wh, short* __restrict__ WhT) {
  int idx = blockIdx.x * 256 + threadIdx.x;
  if (idx >= G4 * PP) return;
  int np = idx % G4, k = idx / G4;
  int j2 = np >> 6, wj = np & 63, ntg = wj >> 4, cc = wj & 15;
  int col = ntg * HH + j2 * 16 + cc;
  WhT[(size_t)np * PP + k] = f2bf(Wh[(size_t)k * G4 + col]);
}

__global__ void k_pb(const float* b0, const float* b1, const float* b2, float* pb) {
  int n = blockIdx.x * 256 + threadIdx.x;
  if (n >= 3 * G4) return;
  int l = n / G4, np = n % G4;
  int j2 = np >> 6, wj = np & 63, ntg = wj >> 4, cc = wj & 15;
  int col = ntg * HH + j2 * 16 + cc;
  pb[n] = (l == 0 ? b0 : (l == 1 ? b1 : b2))[col];
}

__global__ void k_wt(const float* __restrict__ W, float* __restrict__ Wt) {
  int idx = blockIdx.x * 256 + threadIdx.x;
  int q = idx >> 8, p = idx & 255;
  Wt[idx] = W[p * 256 + q];
}

// --------------------------- barrier ---------------------------------------
// slots: per group, 48 epoch flags at 16B stride. arrive = coherent store of
// own epoch; wait = wave0 lanes read all 48 in parallel until all >= target,
// then ONE acquire fence (vL1+L2 invalidate) so cached U reads are fresh.

__device__ __forceinline__ void bar_arrive(int* slots, int j, int tid, int& arr) {
  asm volatile("s_waitcnt vmcnt(0)" ::: "memory");
  __syncthreads();
  ++arr;
  if (tid == 0) st_co_b32(slots + j * 4, arr);
}
__device__ __forceinline__ void bar_wait(const int* slots, int lane, int wv, int arr) {
  if (wv == 0) {
    const int* p = slots + (lane < 48 ? lane : 47) * 4;
    for (;;) {
      int v;
      asm volatile("global_load_dword %0, %1, off sc0 sc1\n\ts_waitcnt vmcnt(0)"
                   : "=v"(v) : "v"(p) : "memory");
      if (__all(v >= arr)) break;
      __builtin_amdgcn_s_sleep(1);
    }
    __builtin_amdgcn_fence(__ATOMIC_ACQUIRE, "agent");
  }
  __syncthreads();
}

// --------------------------- LDS B staging ---------------------------------
// LDS byte = (c<<12) | (wj<<6) | (gi'<<4), gi' = (gi ^ (wj>>1)) & 3

template <int K>
__device__ __forceinline__ void stageB(const short* __restrict__ Bw, char* BsC, int j, int tid) {
  const char* src = (const char*)(Bw + (size_t)j * 64 * K);
  constexpr int UPR = K / 8;
  constexpr int ITERS = 64 * UPR / 256;
  #pragma unroll
  for (int it = 0; it < ITERS; ++it) {
    int u = it * 256 + tid;
    int wj = u / UPR;
    int k0 = (u - wj * UPR) * 8;
    bf16x8 v = *(const bf16x8*)(src + (size_t)wj * (K * 2) + k0 * 2);
    int gi = ((k0 >> 3) ^ (wj >> 1)) & 3;
    *(bf16x8*)(BsC + ((k0 >> 5) << 12) + (wj << 6) + (gi << 4)) = v;
  }
}

// --------------------------- per-layer recurrence --------------------------

template <int CIN, bool DOPROJ, bool DOSUM>
__device__ __forceinline__ void layer_run(
    const char* BsC, short* UtS,
    const short* __restrict__ inS, const int inStr,
    const short* __restrict__ WpT, short* __restrict__ projOut,
    const float* __restrict__ pbL,
    short* __restrict__ U, int* slots,
    float* creg, float* sreg, f32x4* accInit,
    const int g, const int j, const int tid, int& arr)
{
  const int lane = tid & 63, wv = tid >> 6;
  const int c0 = lane & 15, rg = lane >> 4;
  const int row0 = g * 64;

  float bias[4];
  int fbB[4];
  #pragma unroll
  for (int nt = 0; nt < 4; ++nt) {
    bias[nt] = pbL[j * 64 + nt * 16 + c0];
    fbB[nt] = ((nt * 16 + c0) << 6) | (((rg ^ (c0 >> 1)) & 3) << 4);
  }
  const short* wb = DOPROJ ? (WpT + (size_t)(j * 16 + c0) * HH + rg * 8) : nullptr;

  for (int t = 0; t < TT; ++t) {
    const int pw = t & 1, pr = pw ^ 1;
    const short* aX = inS + (size_t)t * NB * inStr + (size_t)(row0 + wv * 16 + c0) * inStr + rg * 8;
    const short* aU = U + (size_t)pr * NB * HH + (size_t)(row0 + wv * 16 + c0) * HH + rg * 8;

    f32x4 zz = {0.f, 0.f, 0.f, 0.f};
    f32x4 acc[4];
    #pragma unroll
    for (int nt = 0; nt < 4; ++nt) acc[nt] = (t == 0) ? accInit[nt] : zz;

    // ---- x-part (cached loads; no recurrent dep; overlaps others' arrival) ----
    bf16x8 xf[CIN];
    #pragma unroll
    for (int c = 0; c < CIN; ++c) xf[c] = *(const bf16x8*)(aX + c * 32);
    #pragma unroll
    for (int c = 0; c < CIN; ++c)
      #pragma unroll
      for (int nt = 0; nt < 4; ++nt)
        acc[nt] = __builtin_amdgcn_mfma_f32_16x16x32_bf16(
            xf[c], *(const bf16x8*)(BsC + (c << 12) + fbB[nt]), acc[nt], 0, 0, 0);

    bf16x8 uf[24];
    if (t > 0) {
      bar_wait(slots, lane, wv, arr);   // includes acquire fence (inv)
      // ---- u-part: CACHED loads (L2-shared across the XCD's 24 WGs) ----
      #pragma unroll
      for (int c = 0; c < 24; ++c) uf[c] = *(const bf16x8*)(aU + c * 32);
      #pragma unroll
      for (int c = 0; c < 24; ++c)
        #pragma unroll
        for (int nt = 0; nt < 4; ++nt)
          acc[nt] = __builtin_amdgcn_mfma_f32_16x16x32_bf16(
              uf[c], *(const bf16x8*)(BsC + ((CIN + c) << 12) + fbB[nt]), acc[nt], 0, 0, 0);
    }

    // ---- gates -> cell update -> u ----
    #pragma unroll
    for (int r = 0; r < 4; ++r) {
      float gi = acc[0][r] + bias[0];
      float gf = acc[1][r] + bias[1];
      float gg = acc[2][r] + bias[2];
      float go = acc[3][r] + bias[3];
      float cc2 = sigf(gf) * creg[r] + sigf(gi) * tanh_(gg);
      creg[r] = cc2;
      float uu = sigf(go) * tanh_(cc2);
      if (DOSUM) sreg[r] += uu;
      UtS[(wv * 16 + rg * 4 + r) * 16 + c0] = f2bf(uu);
    }
    __syncthreads();
    {
      int row = tid >> 2, q = tid & 3;
      i32x2 v = *(const i32x2*)(UtS + row * 16 + q * 4);
      st_co_b64((short*)U + (size_t)pw * NB * HH + (size_t)(row0 + row) * HH + j * 16 + q * 4, v);
    }
    bar_arrive(slots, j, tid, arr);

    // ---- lagged projection h_{t-1} = u_{t-1}@Wp — OFF the barrier path ----
    if (DOPROJ && j < 16 && t > 0) {
      f32x4 pacc = zz;
      #pragma unroll
      for (int c = 0; c < 24; ++c)
        pacc = __builtin_amdgcn_mfma_f32_16x16x32_bf16(
            uf[c], *(const bf16x8*)(wb + c * 32), pacc, 0, 0, 0);
      #pragma unroll
      for (int r = 0; r < 4; ++r) {
        short hv = f2bf(pacc[r]);
        st_co_b16(projOut + (size_t)(t - 1) * NB * PP
                          + (size_t)(row0 + wv * 16 + rg * 4 + r) * PP + j * 16 + c0,
                  (int)hv);
      }
    }
  }
}

// --------------------------- fused persistent kernel -----------------------

__global__ void __launch_bounds__(256, 1) lstm_fused(
    const short* __restrict__ xb,
    const short* __restrict__ B0w, const short* __restrict__ B1w, const short* __restrict__ B2w,
    const float* __restrict__ pb,
    const short* __restrict__ WpT0, const short* __restrict__ WpT1,
    const short* __restrict__ WhT1, const short* __restrict__ WhT2,
    short* __restrict__ U, short* __restrict__ seqH,
    float* __restrict__ S, int* __restrict__ cnts)
{
  extern __shared__ char smem[];
  char* BsC = smem;
  short* UtS = (short*)(smem + 131072);
  const int bx = blockIdx.x;
  const int xcd = bx & 7;
  const int g = xcd >> 1;                       // group <-> XCD pair
  const int j = (xcd & 1) * 24 + (bx >> 3);     // 0..47
  const int tid = threadIdx.x;
  const int lane = tid & 63, wv = tid >> 6, c0 = lane & 15, rg = lane >> 4;
  const int row0 = g * 64;
  int* slots = cnts + g * 192;
  int arr = 0;
  float creg[4] = {0.f, 0.f, 0.f, 0.f}, sreg[4] = {0.f, 0.f, 0.f, 0.f};
  f32x4 zz = {0.f, 0.f, 0.f, 0.f};
  f32x4 accInit[4];
  #pragma unroll
  for (int nt = 0; nt < 4; ++nt) accInit[nt] = zz;

  stageB<864>(B0w, BsC, j, tid);
  __syncthreads();

  layer_run<3, true, false>(BsC, UtS, xb, IIP, WpT0, seqH, pb, U, slots,
                            creg, sreg, accInit, g, j, tid, arr);

  // ======== layer transition 0->1 ========
  bar_wait(slots, lane, wv, arr);
  if (j < 16) {           // tail proj t=399 (U buf 1)
    bf16x8 uf[24];
    const short* aU1 = U + (size_t)1 * NB * HH + (size_t)(row0 + wv * 16 + c0) * HH + rg * 8;
    #pragma unroll
    for (int c = 0; c < 24; ++c) ld_co(&uf[c], aU1 + c * 32);
    WAIT_TIE24(uf);
    const short* wb0 = WpT0 + (size_t)(j * 16 + c0) * HH + rg * 8;
    f32x4 pacc = zz;
    #pragma unroll
    for (int c = 0; c < 24; ++c)
      pacc = __builtin_amdgcn_mfma_f32_16x16x32_bf16(uf[c], *(const bf16x8*)(wb0 + c * 32), pacc, 0, 0, 0);
    #pragma unroll
    for (int r = 0; r < 4; ++r) {
      short hv = f2bf(pacc[r]);
      st_co_b16(seqH + (size_t)399 * NB * PP + (size_t)(row0 + wv * 16 + rg * 4 + r) * PP + j * 16 + c0, (int)hv);
    }
  }
  __threadfence();
  bar_arrive(slots, j, tid, arr);
  bar_wait(slots, lane, wv, arr);
  __threadfence();
  {
    const short* aseq = seqH + (size_t)399 * NB * PP + (size_t)(row0 + wv * 16 + c0) * PP + rg * 8;
    #pragma unroll
    for (int nt = 0; nt < 4; ++nt) accInit[nt] = zz;
    #pragma unroll
    for (int c = 0; c < 8; ++c) {
      bf16x8 a = *(const bf16x8*)(aseq + c * 32);
      #pragma unroll
      for (int nt = 0; nt < 4; ++nt) {
        bf16x8 b = *(const bf16x8*)(WhT1 + (size_t)(j * 64 + nt * 16 + c0) * PP + c * 32 + rg * 8);
        accInit[nt] = __builtin_amdgcn_mfma_f32_16x16x32_bf16(a, b, accInit[nt], 0, 0, 0);
      }
    }
  }
  __syncthreads();
  stageB<1024>(B1w, BsC, j, tid);
  __syncthreads();

  layer_run<8, true, false>(BsC, UtS, seqH, PP, WpT1, seqH, pb + G4, U, slots,
                            creg, sreg, accInit, g, j, tid, arr);

  // ======== layer transition 1->2 ========
  bar_wait(slots, lane, wv, arr);
  if (j < 16) {
    bf16x8 uf[24];
    const short* aU1 = U + (size_t)1 * NB * HH + (size_t)(row0 + wv * 16 + c0) * HH + rg * 8;
    #pragma unroll
    for (int c = 0; c < 24; ++c) ld_co(&uf[c], aU1 + c * 32);
    WAIT_TIE24(uf);
    const short* wb1 = WpT1 + (size_t)(j * 16 + c0) * HH + rg * 8;
    f32x4 pacc = zz;
    #pragma unroll
    for (int c = 0; c < 24; ++c)
      pacc = __builtin_amdgcn_mfma_f32_16x16x32_bf16(uf[c], *(const bf16x8*)(wb1 + c * 32), pacc, 0, 0, 0);
    #pragma unroll
    for (int r = 0; r < 4; ++r) {
      short hv = f2bf(pacc[r]);
      st_co_b16(seqH + (size_t)399 * NB * PP + (size_t)(row0 + wv * 16 + rg * 4 + r) * PP + j * 16 + c0, (int)hv);
    }
  }
  __threadfence();
  bar_arrive(slots, j, tid, arr);
  bar_wait(slots, lane, wv, arr);
  __threadfence();
  {
    const short* aseq = seqH + (size_t)399 * NB * PP + (size_t)(row0 + wv * 16 + c0) * PP + rg * 8;
    #pragma unroll
    for (int nt = 0; nt < 4; ++nt) accInit[nt] = zz;
    #pragma unroll
    for (int c = 0; c < 8; ++c) {
      bf16x8 a = *(const bf16x8*)(aseq + c * 32);
      #pragma unroll
      for (int nt = 0; nt < 4; ++nt) {
        bf16x8 b = *(const bf16x8*)(WhT2 + (size_t)(j * 64 + nt * 16 + c0) * PP + c * 32 + rg * 8);
        accInit[nt] = __builtin_amdgcn_mfma_f32_16x16x32_bf16(a, b, accInit[nt], 0, 0, 0);
      }
    }
  }
  __syncthreads();
  stageB<1024>(B2w, BsC, j, tid);
  __syncthreads();

  layer_run<8, false, true>(BsC, UtS, seqH, PP, nullptr, nullptr, pb + 2 * G4, U, slots,
                            creg, sreg, accInit, g, j, tid, arr);

  // ---- S = sum_t u2 ----
  #pragma unroll
  for (int r = 0; r < 4; ++r)
    S[(size_t)(row0 + wv * 16 + rg * 4 + r) * HH + j * 16 + c0] = sreg[r];
}

// --------------------------- epilogue --------------------------------------

__global__ void k_mh(const float* __restrict__ S, const float* __restrict__ Wp2, float* __restrict__ mh) {
  __shared__ float sl[HH];
  int b = blockIdx.x, p = threadIdx.x;
  for (int i = p; i < HH; i += 256) sl[i] = S[(size_t)b * HH + i] * (1.0f / 400.0f);
  __syncthreads();
  float a = 0.f;
  for (int k = 0; k < HH; ++k) a = fmaf(sl[k], Wp2[(size_t)k * PP + p], a);
  mh[b * PP + p] = a;
}

__global__ void k_out(const float* __restrict__ mh, const float* __restrict__ Wt,
                      const float* __restrict__ lb, float* __restrict__ out) {
  __shared__ float ml[PP];
  __shared__ float red[PP];
  int b = blockIdx.x, p = threadIdx.x;
  ml[p] = mh[b * PP + p];
  __syncthreads();
  float z = lb[p];
  for (int q = 0; q < PP; ++q) z = fmaf(ml[q], Wt[q * PP + p], z);
  z = fmaxf(z, 0.0f);
  red[p] = z * z;
  __syncthreads();
  for (int st = 128; st > 0; st >>= 1) { if (p < st) red[p] += red[p + st]; __syncthreads(); }
  out[b * PP + p] = z / sqrtf(red[0]);
}

// --------------------------- launch ----------------------------------------

extern "C" void kernel_launch(void* const* d_in, const int* in_sizes, int n_in,
                              void* d_out, int out_size, void* d_ws, size_t ws_size,
                              hipStream_t stream) {
  (void)in_sizes; (void)n_in; (void)out_size; (void)ws_size;
  const float* x   = (const float*)d_in[0];
  const float* Wx0 = (const float*)d_in[1];
  const float* Wh0 = (const float*)d_in[2];
  const float* b0  = (const float*)d_in[3];
  const float* Wp0 = (const float*)d_in[4];
  const float* Wx1 = (const float*)d_in[5];
  const float* Wh1 = (const float*)d_in[6];
  const float* b1  = (const float*)d_in[7];
  const float* Wp1 = (const float*)d_in[8];
  const float* Wx2 = (const float*)d_in[9];
  const float* Wh2 = (const float*)d_in[10];
  const float* b2  = (const float*)d_in[11];
  const float* Wp2 = (const float*)d_in[12];
  const float* W   = (const float*)d_in[13];
  const float* lb  = (const float*)d_in[14];

  char* w = (char*)d_ws;
  auto take = [&](size_t bytes) { char* p = w; w += (bytes + 255) & ~(size_t)255; return p; };
  short* xb    = (short*)take((size_t)TT * NB * IIP * 2);
  short* B0w   = (short*)take((size_t)G4 * 864 * 2);
  short* B1w   = (short*)take((size_t)G4 * 1024 * 2);
  short* B2w   = (short*)take((size_t)G4 * 1024 * 2);
  float* pbw   = (float*)take((size_t)3 * G4 * 4);
  short* WpT0  = (short*)take((size_t)PP * HH * 2);
  short* WpT1  = (short*)take((size_t)PP * HH * 2);
  short* WhT1  = (short*)take((size_t)G4 * PP * 2);
  short* WhT2  = (short*)take((size_t)G4 * PP * 2);
  short* U     = (short*)take((size_t)2 * NB * HH * 2);
  short* seqH  = (short*)take((size_t)TT * NB * PP * 2);
  float* Sw    = (float*)take((size_t)NB * HH * 4);
  float* mhw   = (float*)take((size_t)NB * PP * 4);
  float* Wtw   = (float*)take((size_t)PP * PP * 4);
  int*   cnts  = (int*)take(4 * 192 * 4);

  hipMemsetAsync(xb, 0, (size_t)TT * NB * IIP * 2, stream);
  hipMemsetAsync(cnts, 0, 4 * 192 * 4, stream);

  k_xb<<<(TT * NB * 80 + 255) / 256, 256, 0, stream>>>(x, xb);
  k_makeB<<<dim3(12, 864), 256, 0, stream>>>(Wx0, Wp0, Wh0, B0w, 864, 96, 80);
  k_makeB<<<dim3(12, 1024), 256, 0, stream>>>(Wx1, Wp1, Wh1, B1w, 1024, 256, 256);
  k_makeB<<<dim3(12, 1024), 256, 0, stream>>>(Wx2, Wp2, Wh2, B2w, 1024, 256, 256);
  k_wpT<<<(PP * HH + 255) / 256, 256, 0, stream>>>(Wp0, WpT0);
  k_wpT<<<(PP * HH + 255) / 256, 256, 0, stream>>>(Wp1, WpT1);
  k_whT<<<(G4 * PP + 255) / 256, 256, 0, stream>>>(Wh1, WhT1);
  k_whT<<<(G4 * PP + 255) / 256, 256, 0, stream>>>(Wh2, WhT2);
  k_pb<<<(3 * G4 + 255) / 256, 256, 0, stream>>>(b0, b1, b2, pbw);
  k_wt<<<(PP * PP) / 256, 256, 0, stream>>>(W, Wtw);

  hipFuncSetAttribute((const void*)lstm_fused,
                      hipFuncAttributeMaxDynamicSharedMemorySize, SMEMB);
  lstm_fused<<<4 * WGJ, 256, SMEMB, stream>>>(xb, B0w, B1w, B2w, pbw, WpT0, WpT1,
                                              WhT1, WhT2, U, seqH, Sw, cnts);

  k_mh<<<NB, 256, 0, stream>>>(Sw, Wp2, mhw);
  k_out<<<NB, 256, 0, stream>>>(mhw, Wtw, lb, (float*)d_out);
}

// Round 7
// 11293.384 us; speedup vs baseline: 1.0616x; 1.0616x over previous
//
#include <hip/hip_runtime.h>
#include <cstdint>
#include <cstddef>

// ---------------------------------------------------------------------------
// 3-layer LSTMP, folded projection, per-LAYER persistent kernels (3 launches).
//   u_t = o*tanh(c);  gates_t = in_t@Wx + u_{t-1}@(Wp@Wh) + b
//   seq h_t = u_t@Wp (16 of 48 WGs, post-arrive, 1-step lag)
//   c carried across layers via Cw; h carry via k_trans2 -> xg0b (t=0 acc init)
// Geometry: 4 batch-groups (XCD pair) x 48 WGs; WG = 64 rows x 64 gate-cols;
// wave = 16 rows, 4 gate-tiles (gates lane-local). B (up to 128KB) in swizzled
// LDS staged once per kernel.
// Barrier (r7): ONE monotone atomic counter per group (own 4KB page).
// arrive = vmcnt-drain + agent atomicAdd; wait = wave0 polls a single 4B line
// (sc0sc1) with s_sleep(2) backoff, then one acquire fence (L2 inv), then
// CACHED U reads. U writes st_co_b64 (write-through). Proj stores: LDS
// transpose -> coherent b64 (coalesced).
// ---------------------------------------------------------------------------

typedef __attribute__((ext_vector_type(8))) short bf16x8;
typedef __attribute__((ext_vector_type(4))) float f32x4;
typedef __attribute__((ext_vector_type(2))) int i32x2;

#define TT 400
#define NB 256
#define IIP 96
#define HH 768
#define PP 256
#define G4 3072
#define WGJ 48
#define SMEMB (131072 + 2048)

__device__ __forceinline__ short f2bf(float f) {
  unsigned u = __builtin_bit_cast(unsigned, f);
  unsigned r = u + 0x7FFFu + ((u >> 16) & 1u);
  return (short)(r >> 16);
}
__device__ __forceinline__ float sigf(float x) { return 1.0f / (1.0f + __expf(-x)); }
__device__ __forceinline__ float tanh_(float x) { return 1.0f - 2.0f / (__expf(2.0f * x) + 1.0f); }

__device__ __forceinline__ void st_co_b64(void* p, i32x2 v) {
  asm volatile("global_store_dwordx2 %0, %1, off sc0 sc1" :: "v"(p), "v"(v) : "memory");
}
__device__ __forceinline__ int ld_flag(const int* p) {
  int v;
  asm volatile("global_load_dword %0, %1, off sc0 sc1\n\ts_waitcnt vmcnt(0)"
               : "=v"(v) : "v"(p) : "memory");
  return v;
}

// --------------------------- prep kernels ----------------------------------
// n' mapping: j = n'>>6, wj = n'&63, gate = wj>>4, cc = wj&15
//             col = gate*768 + j*16 + cc

__global__ void k_xb(const float* __restrict__ x, short* __restrict__ xb) {
  int idx = blockIdx.x * 256 + threadIdx.x;
  if (idx >= TT * NB * 80) return;
  int i = idx % 80, tb = idx / 80;
  int b = tb % NB, t = tb / NB;
  xb[(size_t)(t * NB + b) * IIP + i] = f2bf(x[(size_t)(b * TT + t) * 80 + i]);
}

__global__ void k_makeB(const float* __restrict__ Wx, const float* __restrict__ Wp,
                        const float* __restrict__ Wh, short* __restrict__ out,
                        int K, int KIN, int INDIM) {
  int np = blockIdx.x * 256 + threadIdx.x;
  int k = blockIdx.y;
  int j2 = np >> 6, wj = np & 63, ntg = wj >> 4, cc = wj & 15;
  int col = ntg * HH + j2 * 16 + cc;
  float v;
  if (k < KIN) {
    v = (k < INDIM) ? Wx[(size_t)k * G4 + col] : 0.0f;
  } else {
    float a = 0.f;
    int kr = k - KIN;
    for (int q = 0; q < PP; ++q)
      a = fmaf(Wp[(size_t)kr * PP + q], Wh[(size_t)q * G4 + col], a);
    v = a;
  }
  out[(size_t)np * K + k] = f2bf(v);
}

__global__ void k_wpT(const float* __restrict__ Wp, short* __restrict__ WpT) {
  int idx = blockIdx.x * 256 + threadIdx.x;
  if (idx >= PP * HH) return;
  int n = idx % PP, k = idx / PP;
  WpT[(size_t)n * HH + k] = f2bf(Wp[(size_t)k * PP + n]);
}

__global__ void k_whT(const float* __restrict__ Wh, short* __restrict__ WhT) {
  int idx = blockIdx.x * 256 + threadIdx.x;
  if (idx >= G4 * PP) return;
  int np = idx % G4, k = idx / G4;
  int j2 = np >> 6, wj = np & 63, ntg = wj >> 4, cc = wj & 15;
  int col = ntg * HH + j2 * 16 + cc;
  WhT[(size_t)np * PP + k] = f2bf(Wh[(size_t)k * G4 + col]);
}

__global__ void k_pb(const float* b0, const float* b1, const float* b2, float* pb) {
  int n = blockIdx.x * 256 + threadIdx.x;
  if (n >= 3 * G4) return;
  int l = n / G4, np = n % G4;
  int j2 = np >> 6, wj = np & 63, ntg = wj >> 4, cc = wj & 15;
  int col = ntg * HH + j2 * 16 + cc;
  pb[n] = (l == 0 ? b0 : (l == 1 ? b1 : b2))[col];
}

__global__ void k_wt(const float* __restrict__ W, float* __restrict__ Wt) {
  int idx = blockIdx.x * 256 + threadIdx.x;
  int q = idx >> 8, p = idx & 255;
  Wt[idx] = W[p * 256 + q];
}

// ---- layer transition: xg0b = h_final @ Wh_next (new 64-col geometry) ----
__global__ void __launch_bounds__(256) k_trans2(
    const short* __restrict__ seqF,   // seqH + 399*NB*PP
    const short* __restrict__ WhT, float* __restrict__ xg0b)
{
  const int blk = blockIdx.x;
  const int g = blk & 3, j = blk >> 2;
  const int tid = threadIdx.x, lane = tid & 63, wv = tid >> 6;
  const int c0 = lane & 15, rg = lane >> 4;
  const int row0 = g * 64;
  const short* aseq = seqF + (size_t)(row0 + wv * 16 + c0) * PP + rg * 8;

  f32x4 zz = {0.f, 0.f, 0.f, 0.f};
  f32x4 acc[4];
  #pragma unroll
  for (int nt = 0; nt < 4; ++nt) acc[nt] = zz;
  #pragma unroll
  for (int c = 0; c < 8; ++c) {
    bf16x8 a = *(const bf16x8*)(aseq + c * 32);
    #pragma unroll
    for (int nt = 0; nt < 4; ++nt) {
      bf16x8 b = *(const bf16x8*)(WhT + (size_t)(j * 64 + nt * 16 + c0) * PP + c * 32 + rg * 8);
      acc[nt] = __builtin_amdgcn_mfma_f32_16x16x32_bf16(a, b, acc[nt], 0, 0, 0);
    }
  }
  #pragma unroll
  for (int nt = 0; nt < 4; ++nt)
    #pragma unroll
    for (int r = 0; r < 4; ++r)
      xg0b[(size_t)(row0 + wv * 16 + rg * 4 + r) * G4 + j * 64 + nt * 16 + c0] = acc[nt][r];
}

// --------------------------- barrier ---------------------------------------

__device__ __forceinline__ void bar_arrive(int* cnt, int tid) {
  asm volatile("s_waitcnt vmcnt(0)" ::: "memory");
  __syncthreads();
  if (tid == 0) {
    int old = __hip_atomic_fetch_add(cnt, 1, __ATOMIC_RELAXED, __HIP_MEMORY_SCOPE_AGENT);
    (void)old;
  }
}
__device__ __forceinline__ void bar_wait(const int* cnt, int wv, int target) {
  if (wv == 0) {
    while (ld_flag(cnt) < target) __builtin_amdgcn_s_sleep(2);
    __builtin_amdgcn_fence(__ATOMIC_ACQUIRE, "agent");
  }
  __syncthreads();
}

// --------------------------- LDS B staging ---------------------------------
// LDS byte = (c<<12) | (wj<<6) | (gi'<<4), gi' = (gi ^ (wj>>1)) & 3

template <int K>
__device__ __forceinline__ void stageB(const short* __restrict__ Bw, char* BsC, int j, int tid) {
  const char* src = (const char*)(Bw + (size_t)j * 64 * K);
  constexpr int UPR = K / 8;
  constexpr int ITERS = 64 * UPR / 256;
  #pragma unroll
  for (int it = 0; it < ITERS; ++it) {
    int u = it * 256 + tid;
    int wj = u / UPR;
    int k0 = (u - wj * UPR) * 8;
    bf16x8 v = *(const bf16x8*)(src + (size_t)wj * (K * 2) + k0 * 2);
    int gi = ((k0 >> 3) ^ (wj >> 1)) & 3;
    *(bf16x8*)(BsC + ((k0 >> 5) << 12) + (wj << 6) + (gi << 4)) = v;
  }
}

// --------------------------- per-layer persistent kernel -------------------

template <int CIN, int DOPROJ, int DOSUM, int USEXG>
__global__ void __launch_bounds__(256, 1) k_layer(
    const short* __restrict__ Bw,
    const short* __restrict__ inS, const int inStr,
    const short* __restrict__ WpT, short* __restrict__ projOut,
    const float* __restrict__ pbL,
    short* __restrict__ U, float* __restrict__ Cw, float* __restrict__ S,
    const float* __restrict__ xg0b, int* __restrict__ cntBase)
{
  extern __shared__ char smem[];
  char* BsC = smem;
  short* UtS = (short*)(smem + 131072);
  const int bx = blockIdx.x;
  const int xcd = bx & 7;
  const int g = xcd >> 1;                       // group <-> XCD pair
  const int j = (xcd & 1) * 24 + (bx >> 3);     // 0..47
  const int tid = threadIdx.x;
  const int lane = tid & 63, wv = tid >> 6, c0 = lane & 15, rg = lane >> 4;
  const int row0 = g * 64;
  int* cnt = (int*)((char*)cntBase + g * 4096); // one counter per group, own page
  constexpr int K = CIN * 32 + 768;

  stageB<K>(Bw, BsC, j, tid);

  float creg[4], sreg[4] = {0.f, 0.f, 0.f, 0.f};
  #pragma unroll
  for (int r = 0; r < 4; ++r)
    creg[r] = USEXG ? Cw[(size_t)(row0 + wv * 16 + rg * 4 + r) * HH + j * 16 + c0] : 0.f;

  float bias[4];
  int fbB[4];
  #pragma unroll
  for (int nt = 0; nt < 4; ++nt) {
    bias[nt] = pbL[j * 64 + nt * 16 + c0];
    fbB[nt] = ((nt * 16 + c0) << 6) | (((rg ^ (c0 >> 1)) & 3) << 4);
  }
  const short* wb = DOPROJ ? (WpT + (size_t)(j * 16 + c0) * HH + rg * 8) : nullptr;
  f32x4 zz = {0.f, 0.f, 0.f, 0.f};

  __syncthreads();

  for (int t = 0; t < TT; ++t) {
    const int pw = t & 1, pr = pw ^ 1;
    const short* aX = inS + (size_t)t * NB * inStr + (size_t)(row0 + wv * 16 + c0) * inStr + rg * 8;
    const short* aU = U + (size_t)pr * NB * HH + (size_t)(row0 + wv * 16 + c0) * HH + rg * 8;

    f32x4 acc[4];
    if (USEXG && t == 0) {
      #pragma unroll
      for (int nt = 0; nt < 4; ++nt)
        #pragma unroll
        for (int r = 0; r < 4; ++r)
          acc[nt][r] = xg0b[(size_t)(row0 + wv * 16 + rg * 4 + r) * G4 + j * 64 + nt * 16 + c0];
    } else {
      #pragma unroll
      for (int nt = 0; nt < 4; ++nt) acc[nt] = zz;
    }

    // ---- x-part (cached; no recurrent dep; overlaps others' arrival) ----
    bf16x8 xf[CIN];
    #pragma unroll
    for (int c = 0; c < CIN; ++c) xf[c] = *(const bf16x8*)(aX + c * 32);
    #pragma unroll
    for (int c = 0; c < CIN; ++c)
      #pragma unroll
      for (int nt = 0; nt < 4; ++nt)
        acc[nt] = __builtin_amdgcn_mfma_f32_16x16x32_bf16(
            xf[c], *(const bf16x8*)(BsC + (c << 12) + fbB[nt]), acc[nt], 0, 0, 0);

    bf16x8 uf[24];
    if (t > 0) {
      bar_wait(cnt, wv, WGJ * t);   // single-line poll + acquire inv
      #pragma unroll
      for (int c = 0; c < 24; ++c) uf[c] = *(const bf16x8*)(aU + c * 32);
      #pragma unroll
      for (int c = 0; c < 24; ++c)
        #pragma unroll
        for (int nt = 0; nt < 4; ++nt)
          acc[nt] = __builtin_amdgcn_mfma_f32_16x16x32_bf16(
              uf[c], *(const bf16x8*)(BsC + ((CIN + c) << 12) + fbB[nt]), acc[nt], 0, 0, 0);
    }

    // ---- gates -> cell update -> u ----
    #pragma unroll
    for (int r = 0; r < 4; ++r) {
      float gi = acc[0][r] + bias[0];
      float gf = acc[1][r] + bias[1];
      float gg = acc[2][r] + bias[2];
      float go = acc[3][r] + bias[3];
      float cc2 = sigf(gf) * creg[r] + sigf(gi) * tanh_(gg);
      creg[r] = cc2;
      float uu = sigf(go) * tanh_(cc2);
      if (DOSUM) sreg[r] += uu;
      UtS[(wv * 16 + rg * 4 + r) * 16 + c0] = f2bf(uu);
    }
    __syncthreads();
    {
      int row = tid >> 2, q = tid & 3;
      i32x2 v = *(const i32x2*)(UtS + row * 16 + q * 4);
      st_co_b64((short*)U + (size_t)pw * NB * HH + (size_t)(row0 + row) * HH + j * 16 + q * 4, v);
    }
    bar_arrive(cnt, tid);

    // ---- lagged projection h_{t-1} = u_{t-1}@Wp — off the barrier path ----
    if (DOPROJ && j < 16 && t > 0) {
      f32x4 pacc = zz;
      #pragma unroll
      for (int c = 0; c < 24; ++c)
        pacc = __builtin_amdgcn_mfma_f32_16x16x32_bf16(
            uf[c], *(const bf16x8*)(wb + c * 32), pacc, 0, 0, 0);
      #pragma unroll
      for (int r = 0; r < 4; ++r)
        UtS[(wv * 16 + rg * 4 + r) * 16 + c0] = f2bf(pacc[r]);
      __syncthreads();
      int row = tid >> 2, q = tid & 3;
      i32x2 v = *(const i32x2*)(UtS + row * 16 + q * 4);
      st_co_b64(projOut + (size_t)(t - 1) * NB * PP + (size_t)(row0 + row) * PP + j * 16 + q * 4, v);
    }
  }

  // ---- tail: proj t=399 (u in U buf 1) ----
  bar_wait(cnt, wv, WGJ * TT);
  if (DOPROJ && j < 16) {
    const short* aU1 = U + (size_t)1 * NB * HH + (size_t)(row0 + wv * 16 + c0) * HH + rg * 8;
    f32x4 pacc = zz;
    #pragma unroll
    for (int c = 0; c < 24; ++c) {
      bf16x8 a = *(const bf16x8*)(aU1 + c * 32);
      pacc = __builtin_amdgcn_mfma_f32_16x16x32_bf16(a, *(const bf16x8*)(wb + c * 32), pacc, 0, 0, 0);
    }
    #pragma unroll
    for (int r = 0; r < 4; ++r)
      UtS[(wv * 16 + rg * 4 + r) * 16 + c0] = f2bf(pacc[r]);
    __syncthreads();
    int row = tid >> 2, q = tid & 3;
    i32x2 v = *(const i32x2*)(UtS + row * 16 + q * 4);
    st_co_b64(projOut + (size_t)399 * NB * PP + (size_t)(row0 + row) * PP + j * 16 + q * 4, v);
  }

  // ---- carry out: c (always), S (layer 2) ----
  #pragma unroll
  for (int r = 0; r < 4; ++r) {
    size_t idx = (size_t)(row0 + wv * 16 + rg * 4 + r) * HH + j * 16 + c0;
    Cw[idx] = creg[r];
    if (DOSUM) S[idx] = sreg[r];
  }
}

// --------------------------- epilogue --------------------------------------

__global__ void k_mh(const float* __restrict__ S, const float* __restrict__ Wp2, float* __restrict__ mh) {
  __shared__ float sl[HH];
  int b = blockIdx.x, p = threadIdx.x;
  for (int i = p; i < HH; i += 256) sl[i] = S[(size_t)b * HH + i] * (1.0f / 400.0f);
  __syncthreads();
  float a = 0.f;
  for (int k = 0; k < HH; ++k) a = fmaf(sl[k], Wp2[(size_t)k * PP + p], a);
  mh[b * PP + p] = a;
}

__global__ void k_out(const float* __restrict__ mh, const float* __restrict__ Wt,
                      const float* __restrict__ lb, float* __restrict__ out) {
  __shared__ float ml[PP];
  __shared__ float red[PP];
  int b = blockIdx.x, p = threadIdx.x;
  ml[p] = mh[b * PP + p];
  __syncthreads();
  float z = lb[p];
  for (int q = 0; q < PP; ++q) z = fmaf(ml[q], Wt[q * PP + p], z);
  z = fmaxf(z, 0.0f);
  red[p] = z * z;
  __syncthreads();
  for (int st = 128; st > 0; st >>= 1) { if (p < st) red[p] += red[p + st]; __syncthreads(); }
  out[b * PP + p] = z / sqrtf(red[0]);
}

// --------------------------- launch ----------------------------------------

extern "C" void kernel_launch(void* const* d_in, const int* in_sizes, int n_in,
                              void* d_out, int out_size, void* d_ws, size_t ws_size,
                              hipStream_t stream) {
  (void)in_sizes; (void)n_in; (void)out_size; (void)ws_size;
  const float* x   = (const float*)d_in[0];
  const float* Wx0 = (const float*)d_in[1];
  const float* Wh0 = (const float*)d_in[2];
  const float* b0  = (const float*)d_in[3];
  const float* Wp0 = (const float*)d_in[4];
  const float* Wx1 = (const float*)d_in[5];
  const float* Wh1 = (const float*)d_in[6];
  const float* b1  = (const float*)d_in[7];
  const float* Wp1 = (const float*)d_in[8];
  const float* Wx2 = (const float*)d_in[9];
  const float* Wh2 = (const float*)d_in[10];
  const float* b2  = (const float*)d_in[11];
  const float* Wp2 = (const float*)d_in[12];
  const float* W   = (const float*)d_in[13];
  const float* lb  = (const float*)d_in[14];

  char* w = (char*)d_ws;
  auto take = [&](size_t bytes) { char* p = w; w += (bytes + 4095) & ~(size_t)4095; return p; };
  short* xb    = (short*)take((size_t)TT * NB * IIP * 2);
  short* B0w   = (short*)take((size_t)G4 * 864 * 2);
  short* B1w   = (short*)take((size_t)G4 * 1024 * 2);
  short* B2w   = (short*)take((size_t)G4 * 1024 * 2);
  float* pbw   = (float*)take((size_t)3 * G4 * 4);
  short* WpT0  = (short*)take((size_t)PP * HH * 2);
  short* WpT1  = (short*)take((size_t)PP * HH * 2);
  short* WhT1  = (short*)take((size_t)G4 * PP * 2);
  short* WhT2  = (short*)take((size_t)G4 * PP * 2);
  short* U     = (short*)take((size_t)2 * NB * HH * 2);
  short* seqH  = (short*)take((size_t)TT * NB * PP * 2);
  float* xg0b  = (float*)take((size_t)NB * G4 * 4);
  float* Cw    = (float*)take((size_t)NB * HH * 4);
  float* Sw    = (float*)take((size_t)NB * HH * 4);
  float* mhw   = (float*)take((size_t)NB * PP * 4);
  float* Wtw   = (float*)take((size_t)PP * PP * 4);
  int*   cnts  = (int*)take(3 * 4 * 4096);   // [layer][group] counters, page-strided

  hipMemsetAsync(xb, 0, (size_t)TT * NB * IIP * 2, stream);
  hipMemsetAsync(cnts, 0, 3 * 4 * 4096, stream);

  k_xb<<<(TT * NB * 80 + 255) / 256, 256, 0, stream>>>(x, xb);
  k_makeB<<<dim3(12, 864), 256, 0, stream>>>(Wx0, Wp0, Wh0, B0w, 864, 96, 80);
  k_makeB<<<dim3(12, 1024), 256, 0, stream>>>(Wx1, Wp1, Wh1, B1w, 1024, 256, 256);
  k_makeB<<<dim3(12, 1024), 256, 0, stream>>>(Wx2, Wp2, Wh2, B2w, 1024, 256, 256);
  k_wpT<<<(PP * HH + 255) / 256, 256, 0, stream>>>(Wp0, WpT0);
  k_wpT<<<(PP * HH + 255) / 256, 256, 0, stream>>>(Wp1, WpT1);
  k_whT<<<(G4 * PP + 255) / 256, 256, 0, stream>>>(Wh1, WhT1);
  k_whT<<<(G4 * PP + 255) / 256, 256, 0, stream>>>(Wh2, WhT2);
  k_pb<<<(3 * G4 + 255) / 256, 256, 0, stream>>>(b0, b1, b2, pbw);
  k_wt<<<(PP * PP) / 256, 256, 0, stream>>>(W, Wtw);

  hipFuncSetAttribute((const void*)k_layer<3, 1, 0, 0>,
                      hipFuncAttributeMaxDynamicSharedMemorySize, SMEMB);
  hipFuncSetAttribute((const void*)k_layer<8, 1, 0, 1>,
                      hipFuncAttributeMaxDynamicSharedMemorySize, SMEMB);
  hipFuncSetAttribute((const void*)k_layer<8, 0, 1, 1>,
                      hipFuncAttributeMaxDynamicSharedMemorySize, SMEMB);

  // layer 0: input xb (stride 96, K=864), proj -> seqH
  k_layer<3, 1, 0, 0><<<4 * WGJ, 256, SMEMB, stream>>>(
      B0w, xb, IIP, WpT0, seqH, pbw + 0 * G4, U, Cw, Sw, xg0b,
      (int*)((char*)cnts + 0 * 16384));
  k_trans2<<<4 * WGJ, 256, 0, stream>>>(seqH + (size_t)399 * NB * PP, WhT1, xg0b);

  // layer 1: input seqH (stride 256, K=1024), proj -> seqH in-place (1-step lag)
  k_layer<8, 1, 0, 1><<<4 * WGJ, 256, SMEMB, stream>>>(
      B1w, seqH, PP, WpT1, seqH, pbw + 1 * G4, U, Cw, Sw, xg0b,
      (int*)((char*)cnts + 1 * 16384));
  k_trans2<<<4 * WGJ, 256, 0, stream>>>(seqH + (size_t)399 * NB * PP, WhT2, xg0b);

  // layer 2: input seqH, no proj, accumulate S
  k_layer<8, 0, 1, 1><<<4 * WGJ, 256, SMEMB, stream>>>(
      B2w, seqH, PP, nullptr, nullptr, pbw + 2 * G4, U, Cw, Sw, xg0b,
      (int*)((char*)cnts + 2 * 16384));

  k_mh<<<NB, 256, 0, stream>>>(Sw, Wp2, mhw);
  k_out<<<NB, 256, 0, stream>>>(mhw, Wtw, lb, (float*)d_out);
}